// Round 10
// baseline (11808.054 us; speedup 1.0000x reference)
//
#include <hip/hip_runtime.h>
#include <hip/hip_bf16.h>

#define T_SEQ   2048
#define HIDDEN  2048
#define NH      32
#define NKV     8
#define HD      64
#define QKV_N   ((NH + 2*NKV) * HD)   // 3072
#define Q_COLS  (NH * HD)             // 2048
#define K_OFF   Q_COLS                // 2048
#define V_OFF   (Q_COLS + NKV * HD)   // 2560
#define SM_SCALE 0.125f               // 64^-0.5
#define ROPE_THETA 500000.0f
#define NEG_INF  -3.0e38f

// ---------------------------------------------------------------------------
// GEMM: C[M,N] = A[M,K] * B[N,K]^T   (both row-major, K contiguous — "NT")
// 128x128 tile, BK=16, 256 threads, 8x8 micro-tile per thread (split 4+4).
// Register-prefetch double buffer (T14 async-stage split).
// ---------------------------------------------------------------------------
__global__ __launch_bounds__(256)
void gemm_nt(const float* __restrict__ A, const float* __restrict__ B,
             float* __restrict__ C, int M, int N, int K) {
    __shared__ float As[16][128 + 4];
    __shared__ float Bs[16][128 + 4];

    const int tid = threadIdx.x;
    const int m0 = blockIdx.y * 128;
    const int n0 = blockIdx.x * 128;
    const int tx = tid & 15;           // col fragment group
    const int ty = tid >> 4;           // row fragment group
    const int lr = tid >> 1;           // staging: row within tile (0..127)
    const int lc = (tid & 1) * 8;      // staging: k-col base (0 or 8)

    float c[8][8] = {};

    const float* Arow = A + (size_t)(m0 + lr) * K + lc;
    const float* Brow = B + (size_t)(n0 + lr) * K + lc;

    // prefetch K-tile 0 into registers
    float4 a0 = *(const float4*)&Arow[0];
    float4 a1 = *(const float4*)&Arow[4];
    float4 b0 = *(const float4*)&Brow[0];
    float4 b1 = *(const float4*)&Brow[4];

    for (int k0 = 0; k0 < K; k0 += 16) {
        As[lc + 0][lr] = a0.x; As[lc + 1][lr] = a0.y;
        As[lc + 2][lr] = a0.z; As[lc + 3][lr] = a0.w;
        As[lc + 4][lr] = a1.x; As[lc + 5][lr] = a1.y;
        As[lc + 6][lr] = a1.z; As[lc + 7][lr] = a1.w;
        Bs[lc + 0][lr] = b0.x; Bs[lc + 1][lr] = b0.y;
        Bs[lc + 2][lr] = b0.z; Bs[lc + 3][lr] = b0.w;
        Bs[lc + 4][lr] = b1.x; Bs[lc + 5][lr] = b1.y;
        Bs[lc + 6][lr] = b1.z; Bs[lc + 7][lr] = b1.w;
        __syncthreads();

        if (k0 + 16 < K) {             // issue next K-tile's loads early
            a0 = *(const float4*)&Arow[k0 + 16];
            a1 = *(const float4*)&Arow[k0 + 20];
            b0 = *(const float4*)&Brow[k0 + 16];
            b1 = *(const float4*)&Brow[k0 + 20];
        }

        #pragma unroll
        for (int k = 0; k < 16; ++k) {
            const float4 av0 = *(const float4*)&As[k][ty * 4];
            const float4 av1 = *(const float4*)&As[k][64 + ty * 4];
            const float4 bv0 = *(const float4*)&Bs[k][tx * 4];
            const float4 bv1 = *(const float4*)&Bs[k][64 + tx * 4];
            const float am[8] = {av0.x, av0.y, av0.z, av0.w,
                                 av1.x, av1.y, av1.z, av1.w};
            const float bm[8] = {bv0.x, bv0.y, bv0.z, bv0.w,
                                 bv1.x, bv1.y, bv1.z, bv1.w};
            #pragma unroll
            for (int i = 0; i < 8; ++i)
                #pragma unroll
                for (int j = 0; j < 8; ++j)
                    c[i][j] = fmaf(am[i], bm[j], c[i][j]);
        }
        __syncthreads();
    }

    #pragma unroll
    for (int i = 0; i < 8; ++i) {
        const int row = m0 + ((i < 4) ? (ty * 4 + i) : (64 + ty * 4 + i - 4));
        float4 v0 = make_float4(c[i][0], c[i][1], c[i][2], c[i][3]);
        float4 v1 = make_float4(c[i][4], c[i][5], c[i][6], c[i][7]);
        *(float4*)&C[(size_t)row * N + n0 + tx * 4]      = v0;
        *(float4*)&C[(size_t)row * N + n0 + 64 + tx * 4] = v1;
    }
}

// ---------------------------------------------------------------------------
// RoPE (neox rotate-half) applied in-place to q (heads 0..31) and k (32..39).
// ---------------------------------------------------------------------------
__global__ __launch_bounds__(256)
void rope_kernel(float* __restrict__ qkv, const int* __restrict__ positions) {
    int idx = blockIdx.x * blockDim.x + threadIdx.x;
    if (idx >= T_SEQ * 40 * 32) return;
    const int i  = idx & 31;            // rotary pair index 0..31
    const int hc = (idx >> 5) % 40;     // head-column 0..39 (q then k)
    const int t  = idx / (40 * 32);

    const float pos = (float)positions[t];
    const float expo = (float)(2 * i) / 64.f;
    const float inv_freq = __powf(ROPE_THETA, -expo);
    const float ang = pos * inv_freq;
    float sv, cv;
    sincosf(ang, &sv, &cv);

    float* p = qkv + (size_t)t * QKV_N + hc * HD + i;
    const float x1 = p[0];
    const float x2 = p[32];
    p[0]  = x1 * cv - x2 * sv;
    p[32] = x2 * cv + x1 * sv;
}

// ---------------------------------------------------------------------------
// Attention helpers — small bodies keep per-key transient pressure bounded
// (round-6 lesson: one 32-key unrolled loop ballooned transient VGPR
// pressure past 256 and spilled the long-lived arrays to scratch).
// ---------------------------------------------------------------------------
__device__ __forceinline__ float dot32(const float* kp, const float4* q4) {
    const float4* kr = (const float4*)kp;
    float acc = 0.f;
    #pragma unroll
    for (int ii = 0; ii < 8; ++ii) {
        const float4 kx = kr[ii];
        const float4 qx = q4[ii];
        acc = fmaf(qx.x, kx.x, acc);
        acc = fmaf(qx.y, kx.y, acc);
        acc = fmaf(qx.z, kx.z, acc);
        acc = fmaf(qx.w, kx.w, acc);
    }
    return acc;
}

__device__ __forceinline__ void pv_acc(const float* vp, float p, float4* o4) {
    const float4* vr = (const float4*)vp;
    #pragma unroll
    for (int ii = 0; ii < 8; ++ii) {
        const float4 vx = vr[ii];
        o4[ii].x = fmaf(p, vx.x, o4[ii].x);
        o4[ii].y = fmaf(p, vx.y, o4[ii].y);
        o4[ii].z = fmaf(p, vx.z, o4[ii].z);
        o4[ii].w = fmaf(p, vx.w, o4[ii].w);
    }
}

// Process 8 keys (tile rows jb..jb+7) with NAMED scalars — no spillable array.
__device__ __forceinline__ void proc_group(
    const float (*Ks)[64], const float (*Vs)[64], int jb, int hoff,
    bool diag, int row, const float4* q4, float4* o4, float& m, float& l) {

    float s0 = dot32(&Ks[jb + 0][hoff], q4);
    float s1 = dot32(&Ks[jb + 1][hoff], q4);
    float s2 = dot32(&Ks[jb + 2][hoff], q4);
    float s3 = dot32(&Ks[jb + 3][hoff], q4);
    float s4 = dot32(&Ks[jb + 4][hoff], q4);
    float s5 = dot32(&Ks[jb + 5][hoff], q4);
    float s6 = dot32(&Ks[jb + 6][hoff], q4);
    float s7 = dot32(&Ks[jb + 7][hoff], q4);

    // sum the two 32-dim halves held by the lane pair (L, L^32)
    s0 += __shfl_xor(s0, 32); s1 += __shfl_xor(s1, 32);
    s2 += __shfl_xor(s2, 32); s3 += __shfl_xor(s3, 32);
    s4 += __shfl_xor(s4, 32); s5 += __shfl_xor(s5, 32);
    s6 += __shfl_xor(s6, 32); s7 += __shfl_xor(s7, 32);

    s0 = (!diag || jb + 0 <= row) ? s0 * SM_SCALE : NEG_INF;
    s1 = (!diag || jb + 1 <= row) ? s1 * SM_SCALE : NEG_INF;
    s2 = (!diag || jb + 2 <= row) ? s2 * SM_SCALE : NEG_INF;
    s3 = (!diag || jb + 3 <= row) ? s3 * SM_SCALE : NEG_INF;
    s4 = (!diag || jb + 4 <= row) ? s4 * SM_SCALE : NEG_INF;
    s5 = (!diag || jb + 5 <= row) ? s5 * SM_SCALE : NEG_INF;
    s6 = (!diag || jb + 6 <= row) ? s6 * SM_SCALE : NEG_INF;
    s7 = (!diag || jb + 7 <= row) ? s7 * SM_SCALE : NEG_INF;

    const float gmax = fmaxf(fmaxf(fmaxf(s0, s1), fmaxf(s2, s3)),
                             fmaxf(fmaxf(s4, s5), fmaxf(s6, s7)));
    const float mnew = fmaxf(m, gmax);
    const float corr = __expf(m - mnew);   // first group ever: exp(-inf)=0
    m = mnew;
    l *= corr;
    #pragma unroll
    for (int ii = 0; ii < 8; ++ii) {
        o4[ii].x *= corr; o4[ii].y *= corr;
        o4[ii].z *= corr; o4[ii].w *= corr;
    }

    float p;
    p = __expf(s0 - mnew); l += p; pv_acc(&Vs[jb + 0][hoff], p, o4);
    p = __expf(s1 - mnew); l += p; pv_acc(&Vs[jb + 1][hoff], p, o4);
    p = __expf(s2 - mnew); l += p; pv_acc(&Vs[jb + 2][hoff], p, o4);
    p = __expf(s3 - mnew); l += p; pv_acc(&Vs[jb + 3][hoff], p, o4);
    p = __expf(s4 - mnew); l += p; pv_acc(&Vs[jb + 4][hoff], p, o4);
    p = __expf(s5 - mnew); l += p; pv_acc(&Vs[jb + 5][hoff], p, o4);
    p = __expf(s6 - mnew); l += p; pv_acc(&Vs[jb + 6][hoff], p, o4);
    p = __expf(s7 - mnew); l += p; pv_acc(&Vs[jb + 7][hoff], p, o4);
}

// ---------------------------------------------------------------------------
// Causal GQA flash attention, fp32 — scratch-free restructure.
// Block = 32 q rows x one kv head; 256 threads = 4 waves = 4 q heads.
// lane = row + 32*half: lane pair shares a q row, each owns 32 head dims.
// Online softmax folded per 8-key group (named scalars, no s[] array).
// __launch_bounds__(256, 2): hard 128-VGPR cap — the allocator must narrow
// its scheduling window instead of spilling (live set ~115 fits); also
// gives 2 blocks/CU. K/V staged in LDS; reg-prefetch double buffer;
// heavy-first dispatch. grid = (64, NKV)
// ---------------------------------------------------------------------------
__global__ __launch_bounds__(256, 2)
void attn_fp32(const float* __restrict__ qkv, float* __restrict__ out) {
    __shared__ float Ks[32][64];
    __shared__ float Vs[32][64];

    const int tid  = threadIdx.x;
    const int lane = tid & 63;
    const int wv   = tid >> 6;          // wave id 0..3 = head-in-group
    const int row  = lane & 31;         // q row within block
    const int half = lane >> 5;         // 0: dims 0-31, 1: dims 32-63
    const int hoff = half * 32;
    const int qb   = 63 - (int)blockIdx.x;  // heavy-first dispatch
    const int kvh  = blockIdx.y;
    const int h    = kvh * 4 + wv;
    const int t    = qb * 32 + row;     // this thread's q row

    // q fragment: this half's 32 dims
    const float* qrow = qkv + (size_t)t * QKV_N + h * HD + hoff;
    float4 q4[8];
    #pragma unroll
    for (int i = 0; i < 8; ++i) q4[i] = *(const float4*)&qrow[i * 4];

    float4 o4[8] = {};
    float m = NEG_INF, l = 0.f;

    // staging: 32x64 tile, 256 threads, 2 float4 each for K and V
    const int sr = tid >> 3;            // row 0..31
    const int sc = (tid & 7) * 8;       // col 0,8,...,56
    const float* Kg = qkv + K_OFF + kvh * HD;
    const float* Vg = qkv + V_OFF + kvh * HD;

    const int ntiles = qb + 1;          // 32-key tiles covering <= qb*32+31

    float4 pk0, pk1, pv0, pv1;

    // stage tile 0
    {
        const size_t g = (size_t)sr * QKV_N + sc;
        pk0 = *(const float4*)&Kg[g];
        pk1 = *(const float4*)&Kg[g + 4];
        pv0 = *(const float4*)&Vg[g];
        pv1 = *(const float4*)&Vg[g + 4];
        *(float4*)&Ks[sr][sc]     = pk0;
        *(float4*)&Ks[sr][sc + 4] = pk1;
        *(float4*)&Vs[sr][sc]     = pv0;
        *(float4*)&Vs[sr][sc + 4] = pv1;
    }

    for (int kt = 0; kt < ntiles; ++kt) {
        __syncthreads();                // LDS writes for tile kt visible

        if (kt + 1 < ntiles) {          // issue next tile's loads early
            const size_t g = (size_t)((kt + 1) * 32 + sr) * QKV_N + sc;
            pk0 = *(const float4*)&Kg[g];
            pk1 = *(const float4*)&Kg[g + 4];
            pv0 = *(const float4*)&Vg[g];
            pv1 = *(const float4*)&Vg[g + 4];
        }

        const bool diag = (kt == qb);   // only the diagonal tile masks
        proc_group(Ks, Vs, 0,  hoff, diag, row, q4, o4, m, l);
        proc_group(Ks, Vs, 8,  hoff, diag, row, q4, o4, m, l);
        proc_group(Ks, Vs, 16, hoff, diag, row, q4, o4, m, l);
        proc_group(Ks, Vs, 24, hoff, diag, row, q4, o4, m, l);

        __syncthreads();                // all waves done with tile kt

        if (kt + 1 < ntiles) {          // commit prefetched tile kt+1
            *(float4*)&Ks[sr][sc]     = pk0;
            *(float4*)&Ks[sr][sc + 4] = pk1;
            *(float4*)&Vs[sr][sc]     = pv0;
            *(float4*)&Vs[sr][sc + 4] = pv1;
        }
    }

    const float inv = 1.f / l;
    float* orow = out + (size_t)t * Q_COLS + h * HD + hoff;
    #pragma unroll
    for (int i = 0; i < 8; ++i) {
        float4 v = o4[i];
        v.x *= inv; v.y *= inv; v.z *= inv; v.w *= inv;
        *(float4*)&orow[i * 4] = v;
    }
}

// ---------------------------------------------------------------------------
extern "C" void kernel_launch(void* const* d_in, const int* in_sizes, int n_in,
                              void* d_out, int out_size, void* d_ws, size_t ws_size,
                              hipStream_t stream) {
    const float* hidden    = (const float*)d_in[0];
    const int*   positions = (const int*)d_in[1];
    const float* w_qkv     = (const float*)d_in[2];
    const float* w_o       = (const float*)d_in[3];
    float* out = (float*)d_out;

    float* qkv  = (float*)d_ws;                          // [T, 3072] 25.2 MB
    float* attn = qkv + (size_t)T_SEQ * QKV_N;           // [T, 2048] 16.8 MB

    // 1) QKV projection: qkv = hidden @ w_qkv^T
    gemm_nt<<<dim3(QKV_N / 128, T_SEQ / 128), 256, 0, stream>>>(
        hidden, w_qkv, qkv, T_SEQ, QKV_N, HIDDEN);

    // 2) RoPE on q and k, in place
    rope_kernel<<<(T_SEQ * 40 * 32 + 255) / 256, 256, 0, stream>>>(qkv, positions);

    // 3) causal GQA attention -> attn [T, NH*HD]
    attn_fp32<<<dim3(T_SEQ / 32, NKV), 256, 0, stream>>>(qkv, attn);

    // 4) output projection: out = attn @ w_o^T
    gemm_nt<<<dim3(HIDDEN / 128, T_SEQ / 128), 256, 0, stream>>>(
        attn, w_o, out, T_SEQ, HIDDEN, Q_COLS);
}

// Round 13
// 6211.240 us; speedup vs baseline: 1.9011x; 1.9011x over previous
//
#include <hip/hip_runtime.h>
#include <hip/hip_bf16.h>

#define T_SEQ   2048
#define HIDDEN  2048
#define NH      32
#define NKV     8
#define HD      64
#define QKV_N   ((NH + 2*NKV) * HD)   // 3072
#define Q_COLS  (NH * HD)             // 2048
#define K_OFF   Q_COLS                // 2048
#define V_OFF   (Q_COLS + NKV * HD)   // 2560
#define SM_SCALE 0.125f               // 64^-0.5
#define ROPE_THETA 500000.0f
#define NEG_INF  -3.0e38f

// ---------------------------------------------------------------------------
// GEMM: C[M,N] = A[M,K] * B[N,K]^T   (both row-major, K contiguous — "NT")
// 128x128 tile, BK=16, 256 threads, 8x8 micro-tile per thread (split 4+4).
// Register-prefetch double buffer (T14 async-stage split).
// ---------------------------------------------------------------------------
__global__ __launch_bounds__(256)
void gemm_nt(const float* __restrict__ A, const float* __restrict__ B,
             float* __restrict__ C, int M, int N, int K) {
    __shared__ float As[16][128 + 4];
    __shared__ float Bs[16][128 + 4];

    const int tid = threadIdx.x;
    const int m0 = blockIdx.y * 128;
    const int n0 = blockIdx.x * 128;
    const int tx = tid & 15;           // col fragment group
    const int ty = tid >> 4;           // row fragment group
    const int lr = tid >> 1;           // staging: row within tile (0..127)
    const int lc = (tid & 1) * 8;      // staging: k-col base (0 or 8)

    float c[8][8] = {};

    const float* Arow = A + (size_t)(m0 + lr) * K + lc;
    const float* Brow = B + (size_t)(n0 + lr) * K + lc;

    // prefetch K-tile 0 into registers
    float4 a0 = *(const float4*)&Arow[0];
    float4 a1 = *(const float4*)&Arow[4];
    float4 b0 = *(const float4*)&Brow[0];
    float4 b1 = *(const float4*)&Brow[4];

    for (int k0 = 0; k0 < K; k0 += 16) {
        As[lc + 0][lr] = a0.x; As[lc + 1][lr] = a0.y;
        As[lc + 2][lr] = a0.z; As[lc + 3][lr] = a0.w;
        As[lc + 4][lr] = a1.x; As[lc + 5][lr] = a1.y;
        As[lc + 6][lr] = a1.z; As[lc + 7][lr] = a1.w;
        Bs[lc + 0][lr] = b0.x; Bs[lc + 1][lr] = b0.y;
        Bs[lc + 2][lr] = b0.z; Bs[lc + 3][lr] = b0.w;
        Bs[lc + 4][lr] = b1.x; Bs[lc + 5][lr] = b1.y;
        Bs[lc + 6][lr] = b1.z; Bs[lc + 7][lr] = b1.w;
        __syncthreads();

        if (k0 + 16 < K) {             // issue next K-tile's loads early
            a0 = *(const float4*)&Arow[k0 + 16];
            a1 = *(const float4*)&Arow[k0 + 20];
            b0 = *(const float4*)&Brow[k0 + 16];
            b1 = *(const float4*)&Brow[k0 + 20];
        }

        #pragma unroll
        for (int k = 0; k < 16; ++k) {
            const float4 av0 = *(const float4*)&As[k][ty * 4];
            const float4 av1 = *(const float4*)&As[k][64 + ty * 4];
            const float4 bv0 = *(const float4*)&Bs[k][tx * 4];
            const float4 bv1 = *(const float4*)&Bs[k][64 + tx * 4];
            const float am[8] = {av0.x, av0.y, av0.z, av0.w,
                                 av1.x, av1.y, av1.z, av1.w};
            const float bm[8] = {bv0.x, bv0.y, bv0.z, bv0.w,
                                 bv1.x, bv1.y, bv1.z, bv1.w};
            #pragma unroll
            for (int i = 0; i < 8; ++i)
                #pragma unroll
                for (int j = 0; j < 8; ++j)
                    c[i][j] = fmaf(am[i], bm[j], c[i][j]);
        }
        __syncthreads();
    }

    #pragma unroll
    for (int i = 0; i < 8; ++i) {
        const int row = m0 + ((i < 4) ? (ty * 4 + i) : (64 + ty * 4 + i - 4));
        float4 v0 = make_float4(c[i][0], c[i][1], c[i][2], c[i][3]);
        float4 v1 = make_float4(c[i][4], c[i][5], c[i][6], c[i][7]);
        *(float4*)&C[(size_t)row * N + n0 + tx * 4]      = v0;
        *(float4*)&C[(size_t)row * N + n0 + 64 + tx * 4] = v1;
    }
}

// ---------------------------------------------------------------------------
// RoPE (neox rotate-half) applied in-place to q (heads 0..31) and k (32..39).
// ---------------------------------------------------------------------------
__global__ __launch_bounds__(256)
void rope_kernel(float* __restrict__ qkv, const int* __restrict__ positions) {
    int idx = blockIdx.x * blockDim.x + threadIdx.x;
    if (idx >= T_SEQ * 40 * 32) return;
    const int i  = idx & 31;            // rotary pair index 0..31
    const int hc = (idx >> 5) % 40;     // head-column 0..39 (q then k)
    const int t  = idx / (40 * 32);

    const float pos = (float)positions[t];
    const float expo = (float)(2 * i) / 64.f;
    const float inv_freq = __powf(ROPE_THETA, -expo);
    const float ang = pos * inv_freq;
    float sv, cv;
    sincosf(ang, &sv, &cv);

    float* p = qkv + (size_t)t * QKV_N + hc * HD + i;
    const float x1 = p[0];
    const float x2 = p[32];
    p[0]  = x1 * cv - x2 * sv;
    p[32] = x2 * cv + x1 * sv;
}

// ---------------------------------------------------------------------------
// Causal GQA flash attention, fp32 — ZERO-ARRAY version.
// Rounds 6+10 post-mortem: float4 ARRAYS (q4[8]/o4[8]) passed by pointer
// kept landing in scratch; kernel was scratch-LATENCY-bound (identical
// 11.2 ms at different traffic volumes, VALUBusy 2%). This version has NO
// local arrays and NO address-taken locals: all state is named float4
// scalars manipulated via macros.
//
// Layout: block = 16 q rows x one kv head; 256 threads = 4 waves = the 4
// q heads of the kv group. lane = quarter*16 + row: 4 lanes per q row,
// each owning 16 of the 64 head dims (q0..q3, o0..o3 = 32 VGPR total).
// Score = 16-FMA partial dot + butterfly __shfl_xor(16|32).
// K/V tile (32x64) staged in LDS, shared by all 4 waves; T14 register
// prefetch double-buffer; heavy-first dispatch (qb = 127-bx).
// __launch_bounds__(256,2): 128-VGPR cap (live ~85), 2 blocks/CU.
// grid = (128, NKV)
// ---------------------------------------------------------------------------

#define DOT16(dst, R) do {                                                  \
    const float4 ka = *(const float4*)&Ks[R][qoff];                         \
    const float4 kb = *(const float4*)&Ks[R][qoff + 4];                     \
    const float4 kc = *(const float4*)&Ks[R][qoff + 8];                     \
    const float4 kd = *(const float4*)&Ks[R][qoff + 12];                    \
    float acc = 0.f;                                                        \
    acc = fmaf(q0.x, ka.x, acc); acc = fmaf(q0.y, ka.y, acc);               \
    acc = fmaf(q0.z, ka.z, acc); acc = fmaf(q0.w, ka.w, acc);               \
    acc = fmaf(q1.x, kb.x, acc); acc = fmaf(q1.y, kb.y, acc);               \
    acc = fmaf(q1.z, kb.z, acc); acc = fmaf(q1.w, kb.w, acc);               \
    acc = fmaf(q2.x, kc.x, acc); acc = fmaf(q2.y, kc.y, acc);               \
    acc = fmaf(q2.z, kc.z, acc); acc = fmaf(q2.w, kc.w, acc);               \
    acc = fmaf(q3.x, kd.x, acc); acc = fmaf(q3.y, kd.y, acc);               \
    acc = fmaf(q3.z, kd.z, acc); acc = fmaf(q3.w, kd.w, acc);               \
    dst = acc;                                                              \
} while (0)

#define PV16(R, P) do {                                                     \
    const float4 va = *(const float4*)&Vs[R][qoff];                         \
    const float4 vb = *(const float4*)&Vs[R][qoff + 4];                     \
    const float4 vc = *(const float4*)&Vs[R][qoff + 8];                     \
    const float4 vd = *(const float4*)&Vs[R][qoff + 12];                    \
    o0.x = fmaf(P, va.x, o0.x); o0.y = fmaf(P, va.y, o0.y);                 \
    o0.z = fmaf(P, va.z, o0.z); o0.w = fmaf(P, va.w, o0.w);                 \
    o1.x = fmaf(P, vb.x, o1.x); o1.y = fmaf(P, vb.y, o1.y);                 \
    o1.z = fmaf(P, vb.z, o1.z); o1.w = fmaf(P, vb.w, o1.w);                 \
    o2.x = fmaf(P, vc.x, o2.x); o2.y = fmaf(P, vc.y, o2.y);                 \
    o2.z = fmaf(P, vc.z, o2.z); o2.w = fmaf(P, vc.w, o2.w);                 \
    o3.x = fmaf(P, vd.x, o3.x); o3.y = fmaf(P, vd.y, o3.y);                 \
    o3.z = fmaf(P, vd.z, o3.z); o3.w = fmaf(P, vd.w, o3.w);                 \
} while (0)

#define PROC8(JB) do {                                                      \
    float s0, s1, s2, s3, s4, s5, s6, s7;                                   \
    DOT16(s0, (JB) + 0); DOT16(s1, (JB) + 1);                               \
    DOT16(s2, (JB) + 2); DOT16(s3, (JB) + 3);                               \
    DOT16(s4, (JB) + 4); DOT16(s5, (JB) + 5);                               \
    DOT16(s6, (JB) + 6); DOT16(s7, (JB) + 7);                               \
    s0 += __shfl_xor(s0, 16); s0 += __shfl_xor(s0, 32);                     \
    s1 += __shfl_xor(s1, 16); s1 += __shfl_xor(s1, 32);                     \
    s2 += __shfl_xor(s2, 16); s2 += __shfl_xor(s2, 32);                     \
    s3 += __shfl_xor(s3, 16); s3 += __shfl_xor(s3, 32);                     \
    s4 += __shfl_xor(s4, 16); s4 += __shfl_xor(s4, 32);                     \
    s5 += __shfl_xor(s5, 16); s5 += __shfl_xor(s5, 32);                     \
    s6 += __shfl_xor(s6, 16); s6 += __shfl_xor(s6, 32);                     \
    s7 += __shfl_xor(s7, 16); s7 += __shfl_xor(s7, 32);                     \
    s0 = (!diag || (JB) + 0 <= rloc) ? s0 * SM_SCALE : NEG_INF;             \
    s1 = (!diag || (JB) + 1 <= rloc) ? s1 * SM_SCALE : NEG_INF;             \
    s2 = (!diag || (JB) + 2 <= rloc) ? s2 * SM_SCALE : NEG_INF;             \
    s3 = (!diag || (JB) + 3 <= rloc) ? s3 * SM_SCALE : NEG_INF;             \
    s4 = (!diag || (JB) + 4 <= rloc) ? s4 * SM_SCALE : NEG_INF;             \
    s5 = (!diag || (JB) + 5 <= rloc) ? s5 * SM_SCALE : NEG_INF;             \
    s6 = (!diag || (JB) + 6 <= rloc) ? s6 * SM_SCALE : NEG_INF;             \
    s7 = (!diag || (JB) + 7 <= rloc) ? s7 * SM_SCALE : NEG_INF;             \
    const float gmax = fmaxf(fmaxf(fmaxf(s0, s1), fmaxf(s2, s3)),           \
                             fmaxf(fmaxf(s4, s5), fmaxf(s6, s7)));          \
    const float mnew = fmaxf(m, gmax);                                      \
    const float corr = __expf(m - mnew);                                    \
    m = mnew;                                                               \
    l *= corr;                                                              \
    o0.x *= corr; o0.y *= corr; o0.z *= corr; o0.w *= corr;                 \
    o1.x *= corr; o1.y *= corr; o1.z *= corr; o1.w *= corr;                 \
    o2.x *= corr; o2.y *= corr; o2.z *= corr; o2.w *= corr;                 \
    o3.x *= corr; o3.y *= corr; o3.z *= corr; o3.w *= corr;                 \
    float p;                                                                \
    p = __expf(s0 - mnew); l += p; PV16((JB) + 0, p);                       \
    p = __expf(s1 - mnew); l += p; PV16((JB) + 1, p);                       \
    p = __expf(s2 - mnew); l += p; PV16((JB) + 2, p);                       \
    p = __expf(s3 - mnew); l += p; PV16((JB) + 3, p);                       \
    p = __expf(s4 - mnew); l += p; PV16((JB) + 4, p);                       \
    p = __expf(s5 - mnew); l += p; PV16((JB) + 5, p);                       \
    p = __expf(s6 - mnew); l += p; PV16((JB) + 6, p);                       \
    p = __expf(s7 - mnew); l += p; PV16((JB) + 7, p);                       \
} while (0)

__global__ __launch_bounds__(256, 2)
void attn_fp32(const float* __restrict__ qkv, float* __restrict__ out) {
    __shared__ float Ks[32][64];
    __shared__ float Vs[32][64];

    const int tid     = threadIdx.x;
    const int lane    = tid & 63;
    const int wv      = tid >> 6;         // wave id 0..3 = head-in-group
    const int row     = lane & 15;        // q row within block
    const int quarter = lane >> 4;        // 0..3: which 16 dims
    const int qoff    = quarter * 16;
    const int qb      = 127 - (int)blockIdx.x;   // heavy-first dispatch
    const int kvh     = blockIdx.y;
    const int h       = kvh * 4 + wv;
    const int t       = qb * 16 + row;    // this thread's q row

    // q fragment: named float4 scalars (NO array)
    const float* qrow = qkv + (size_t)t * QKV_N + h * HD + qoff;
    float4 q0 = *(const float4*)&qrow[0];
    float4 q1 = *(const float4*)&qrow[4];
    float4 q2 = *(const float4*)&qrow[8];
    float4 q3 = *(const float4*)&qrow[12];

    float4 o0 = {0.f, 0.f, 0.f, 0.f}, o1 = {0.f, 0.f, 0.f, 0.f};
    float4 o2 = {0.f, 0.f, 0.f, 0.f}, o3 = {0.f, 0.f, 0.f, 0.f};
    float m = NEG_INF, l = 0.f;

    // staging: 32x64 tile, 256 threads, 2 float4 each for K and V
    const int sr = tid >> 3;              // row 0..31
    const int sc = (tid & 7) * 8;         // col 0,8,...,56
    const float* Kg = qkv + K_OFF + kvh * HD;
    const float* Vg = qkv + V_OFF + kvh * HD;

    const int ntiles = (16 * qb + 47) >> 5;   // 32-key tiles covering <= t

    float4 pk0, pk1, pv0, pv1;

    // stage tile 0
    {
        const size_t g = (size_t)sr * QKV_N + sc;
        pk0 = *(const float4*)&Kg[g];
        pk1 = *(const float4*)&Kg[g + 4];
        pv0 = *(const float4*)&Vg[g];
        pv1 = *(const float4*)&Vg[g + 4];
        *(float4*)&Ks[sr][sc]     = pk0;
        *(float4*)&Ks[sr][sc + 4] = pk1;
        *(float4*)&Vs[sr][sc]     = pv0;
        *(float4*)&Vs[sr][sc + 4] = pv1;
    }

    for (int kt = 0; kt < ntiles; ++kt) {
        __syncthreads();                  // LDS writes for tile kt visible

        if (kt + 1 < ntiles) {            // issue next tile's loads early
            const size_t g = (size_t)((kt + 1) * 32 + sr) * QKV_N + sc;
            pk0 = *(const float4*)&Kg[g];
            pk1 = *(const float4*)&Kg[g + 4];
            pv0 = *(const float4*)&Vg[g];
            pv1 = *(const float4*)&Vg[g + 4];
        }

        const bool diag = (kt == ntiles - 1);   // only last tile can mask
        const int  rloc = t - kt * 32;          // local causal limit
        PROC8(0);
        PROC8(8);
        PROC8(16);
        PROC8(24);

        __syncthreads();                  // all waves done with tile kt

        if (kt + 1 < ntiles) {            // commit prefetched tile kt+1
            *(float4*)&Ks[sr][sc]     = pk0;
            *(float4*)&Ks[sr][sc + 4] = pk1;
            *(float4*)&Vs[sr][sc]     = pv0;
            *(float4*)&Vs[sr][sc + 4] = pv1;
        }
    }

    const float inv = 1.f / l;
    float* orow = out + (size_t)t * Q_COLS + h * HD + qoff;
    float4 w0 = o0, w1 = o1, w2 = o2, w3 = o3;
    w0.x *= inv; w0.y *= inv; w0.z *= inv; w0.w *= inv;
    w1.x *= inv; w1.y *= inv; w1.z *= inv; w1.w *= inv;
    w2.x *= inv; w2.y *= inv; w2.z *= inv; w2.w *= inv;
    w3.x *= inv; w3.y *= inv; w3.z *= inv; w3.w *= inv;
    *(float4*)&orow[0]  = w0;
    *(float4*)&orow[4]  = w1;
    *(float4*)&orow[8]  = w2;
    *(float4*)&orow[12] = w3;
}

// ---------------------------------------------------------------------------
extern "C" void kernel_launch(void* const* d_in, const int* in_sizes, int n_in,
                              void* d_out, int out_size, void* d_ws, size_t ws_size,
                              hipStream_t stream) {
    const float* hidden    = (const float*)d_in[0];
    const int*   positions = (const int*)d_in[1];
    const float* w_qkv     = (const float*)d_in[2];
    const float* w_o       = (const float*)d_in[3];
    float* out = (float*)d_out;

    float* qkv  = (float*)d_ws;                          // [T, 3072] 25.2 MB
    float* attn = qkv + (size_t)T_SEQ * QKV_N;           // [T, 2048] 16.8 MB

    // 1) QKV projection: qkv = hidden @ w_qkv^T
    gemm_nt<<<dim3(QKV_N / 128, T_SEQ / 128), 256, 0, stream>>>(
        hidden, w_qkv, qkv, T_SEQ, QKV_N, HIDDEN);

    // 2) RoPE on q and k, in place
    rope_kernel<<<(T_SEQ * 40 * 32 + 255) / 256, 256, 0, stream>>>(qkv, positions);

    // 3) causal GQA attention -> attn [T, NH*HD]
    attn_fp32<<<dim3(T_SEQ / 16, NKV), 256, 0, stream>>>(qkv, attn);

    // 4) output projection: out = attn @ w_o^T
    gemm_nt<<<dim3(HIDDEN / 128, T_SEQ / 128), 256, 0, stream>>>(
        attn, w_o, out, T_SEQ, HIDDEN, Q_COLS);
}